// Round 2
// baseline (4307.919 us; speedup 1.0000x reference)
//
#include <hip/hip_runtime.h>

#define T_SEQ 512
#define HID 256

typedef _Float16 half8 __attribute__((ext_vector_type(8)));
typedef _Float16 half4 __attribute__((ext_vector_type(4)));
typedef float floatx4 __attribute__((ext_vector_type(4)));

// ws layout (f16 elements): gh frags | gi frags | w_base frags | w_dir/mag frags
#define OFF_GH 0
#define OFF_GI (OFF_GH + 384 * 512)
#define OFF_WB (OFF_GI + 96 * 512)
#define OFF_WD (OFF_WB + 128 * 512)

#define MFMA16(A, B, C) __builtin_amdgcn_mfma_f32_16x16x32_f16(A, B, C, 0, 0, 0)

__device__ __forceinline__ float sigm(float x) { return 1.0f / (1.0f + __expf(-x)); }
__device__ __forceinline__ float tanh_fast(float x) {
  float e = __expf(2.0f * x);
  return 1.0f - 2.0f / (e + 1.0f);
}

// Pack all weights (fp32 in) into f16 MFMA B-fragment order.
__global__ void prep_kernel(const float* __restrict__ w_ih,
                            const float* __restrict__ w_hh,
                            const float* __restrict__ w_base,
                            const float* __restrict__ w_dir,
                            const float* __restrict__ w_mag,
                            _Float16* __restrict__ ws) {
  const int f = blockIdx.x;
  const int lane = threadIdx.x;
  const int col = lane & 15, quad = lane >> 4;
  const float* src;
  int n, k, ld;
  _Float16* dst;
  if (f < 384) {  // w_hh frags: f = (w*8 + kt)*6 + nt ; nt: 0,1=r 2,3=z 4,5=n
    int nt = f % 6, kt = (f / 6) % 8, w = f / 48;
    n = (nt >> 1) * 256 + w * 32 + (nt & 1) * 16 + col;
    k = kt * 32 + quad * 8;
    src = w_hh; ld = 256;
    dst = ws + OFF_GH + ((w * 8 + kt) * 6 + nt) * 512 + lane * 8;
  } else if (f < 480) {  // w_ih frags: f2 = (w*2 + kt)*6 + nt
    int f2 = f - 384;
    int nt = f2 % 6, kt = (f2 / 6) % 2, w = f2 / 12;
    n = (nt >> 1) * 256 + w * 32 + (nt & 1) * 16 + col;
    k = kt * 32 + quad * 8;
    src = w_ih; ld = 64;
    dst = ws + OFF_GI + ((w * 2 + kt) * 6 + nt) * 512 + lane * 8;
  } else if (f < 608) {  // w_base frags
    int f3 = f - 480;
    int nt = f3 % 2, kt = (f3 / 2) % 8, w = f3 / 16;
    n = w * 32 + nt * 16 + col;
    k = kt * 32 + quad * 8;
    src = w_base; ld = 256;
    dst = ws + OFF_WB + ((w * 8 + kt) * 2 + nt) * 512 + lane * 8;
  } else {  // dir/mag combined: cols 0..7 dir, 8..15 mag
    int kt = f - 608;
    k = kt * 32 + quad * 8;
    ld = 256;
    if (col < 8) { src = w_dir; n = col; } else { src = w_mag; n = col - 8; }
    dst = ws + OFF_WD + kt * 512 + lane * 8;
  }
#pragma unroll
  for (int j = 0; j < 8; ++j)
    dst[j] = (_Float16)src[n * ld + k + j];
}

// Single self-contained sequential kernel: 64 blocks (16 batch rows each) x
// 512 threads, 1 block/CU. Per step: 60 MFMAs — 40 register-resident gh frags,
// 12 register-resident gi (w_ih) frags fed by x prefetched one step ahead,
// 8 gh frags streamed from L2. No gi precompute, no inter-launch state, no
// cross-block communication: each block owns its rows end-to-end.
__global__ __launch_bounds__(512, 1)
void gru_all_kernel(const float* __restrict__ x_seq,
                    const float* __restrict__ b_ih,
                    const float* __restrict__ b_hh,
                    const float* __restrict__ b_base,
                    const float* __restrict__ b_dir,
                    const float* __restrict__ b_mag,
                    const _Float16* __restrict__ ws,
                    float* __restrict__ out) {
  __shared__ __align__(16) _Float16 hlin[2][4096];  // [kt(8)][q(4)][row(16)][8]

  const int tid = threadIdx.x;
  const int lane = tid & 63;
  const int w = tid >> 6;
  const int col = lane & 15;
  const int quad = lane >> 4;
  const int row0 = blockIdx.x * 16;

  // biases (folded; n-gate input/hidden kept separate for r*(h_n) form)
  float br[2], bz[2], bin_[2], bhn[2];
#pragma unroll
  for (int s = 0; s < 2; ++s) {
    const int c = w * 32 + s * 16 + col;
    br[s] = b_ih[c] + b_hh[c];
    bz[s] = b_ih[256 + c] + b_hh[256 + c];
    bin_[s] = b_ih[512 + c];
    bhn[s] = b_hh[512 + c];
  }

  float hreg[2][4];
#pragma unroll
  for (int s = 0; s < 2; ++s)
#pragma unroll
    for (int r2 = 0; r2 < 4; ++r2) hreg[s][r2] = 0.0f;
  *(half8*)&hlin[0][tid * 8] = (half8)((_Float16)0.0f);

  const half8* __restrict__ ghp = (const half8*)(ws + OFF_GH) + w * (48 * 64);
  const half8* __restrict__ gip = (const half8*)(ws + OFF_GI) + w * (12 * 64);
  const half8* __restrict__ wbp = (const half8*)(ws + OFF_WB) + w * (16 * 64);
  const half8* __restrict__ wdp = (const half8*)(ws + OFF_WD);

  // register-resident weights: 40 gh frags + all 12 gi frags
  half8 wreg[40];
#pragma unroll
  for (int f = 0; f < 40; ++f) wreg[f] = ghp[f * 64 + lane];
  half8 wg[12];
#pragma unroll
  for (int f = 0; f < 12; ++f) wg[f] = gip[f * 64 + lane];

  const float* const xlane =
      x_seq + (size_t)(row0 + col) * (T_SEQ * 64) + quad * 8;
  float4 xc[4], xn[4];
  {
    const float* p = xlane;  // t = 0
    xc[0] = *(const float4*)(p);
    xc[1] = *(const float4*)(p + 4);
    xc[2] = *(const float4*)(p + 32);
    xc[3] = *(const float4*)(p + 36);
  }

  auto body = [&](int tpre, int cur, float4* xcur, float4* xnext) {
    __syncthreads();
    const _Float16* hc = hlin[cur];
    _Float16* hn = hlin[cur ^ 1];

    // streamed gh frags f40..47 FIRST (L2; oldest in vmcnt order), then the
    // x prefetch for the NEXT step (consumed a full body later).
    half8 st[8];
#pragma unroll
    for (int i = 0; i < 8; ++i) st[i] = ghp[(40 + i) * 64 + lane];
    {
      const float* p = xlane + (size_t)tpre * 64;
      xnext[0] = *(const float4*)(p);
      xnext[1] = *(const float4*)(p + 4);
      xnext[2] = *(const float4*)(p + 32);
      xnext[3] = *(const float4*)(p + 36);
    }

    half8 ah[8];
#pragma unroll
    for (int kt = 0; kt < 8; ++kt)
      ah[kt] = *(const half8*)&hc[kt * 512 + lane * 8];

    half8 ax0, ax1;
#pragma unroll
    for (int j = 0; j < 4; ++j) {
      ax0[j]     = (_Float16)((const float*)&xcur[0])[j];
      ax0[4 + j] = (_Float16)((const float*)&xcur[1])[j];
      ax1[j]     = (_Float16)((const float*)&xcur[2])[j];
      ax1[4 + j] = (_Float16)((const float*)&xcur[3])[j];
    }

    // acc 0,1=r(h) 2,3=z(h) 4,5=n(h-side) 6,7=n(x-side); x r/z fold into 0..3
    floatx4 acc[8];
#pragma unroll
    for (int i = 0; i < 8; ++i) acc[i] = (floatx4){0.f, 0.f, 0.f, 0.f};

    __builtin_amdgcn_s_setprio(1);
#pragma unroll
    for (int f = 0; f < 40; ++f)
      acc[f % 6] = MFMA16(ah[f / 6], wreg[f], acc[f % 6]);
    // gi MFMAs (register inputs) fill the window while st completes
#pragma unroll
    for (int kt2 = 0; kt2 < 2; ++kt2) {
      const half8 ax = kt2 ? ax1 : ax0;
#pragma unroll
      for (int nt = 0; nt < 6; ++nt) {
        const int aidx = (nt < 4) ? nt : nt + 2;
        acc[aidx] = MFMA16(ax, wg[kt2 * 6 + nt], acc[aidx]);
      }
    }
#pragma unroll
    for (int i = 0; i < 8; ++i) {
      const int f = 40 + i;
      acc[f % 6] = MFMA16(ah[f / 6], st[i], acc[f % 6]);
    }
    __builtin_amdgcn_s_setprio(0);

    // epilogue
#pragma unroll
    for (int s = 0; s < 2; ++s) {
      const int inner = s * 16 + col;
      const int widx = w * 512 + (inner >> 3) * 128 + (col & 7);
#pragma unroll
      for (int r2 = 0; r2 < 4; ++r2) {
        const float rr = sigm(acc[0 + s][r2] + br[s]);
        const float zz = sigm(acc[2 + s][r2] + bz[s]);
        const float nn =
            tanh_fast(acc[6 + s][r2] + bin_[s] + rr * (acc[4 + s][r2] + bhn[s]));
        const float hnew = zz * hreg[s][r2] + (1.0f - zz) * nn;
        hreg[s][r2] = hnew;
        hn[widx + (quad * 4 + r2) * 8] = (_Float16)hnew;
      }
    }
  };

#pragma unroll 1
  for (int t = 0; t < T_SEQ; t += 2) {
    body(t + 1, 0, xc, xn);
    const int tp2 = (t + 2 < T_SEQ) ? (t + 2) : (T_SEQ - 1);
    body(tp2, 1, xn, xc);
  }

  __syncthreads();
  // head: base = relu(hT @ w_base^T + b_base); h_T in hlin[0] (T even)
  {
    floatx4 ab[2];
    ab[0] = (floatx4){0.f, 0.f, 0.f, 0.f};
    ab[1] = (floatx4){0.f, 0.f, 0.f, 0.f};
#pragma unroll
    for (int kt = 0; kt < 8; ++kt) {
      const half8 ahh = *(const half8*)&hlin[0][kt * 512 + lane * 8];
      const half8* bp = wbp + kt * (2 * 64) + lane;
      ab[0] = MFMA16(ahh, bp[0],  ab[0]);
      ab[1] = MFMA16(ahh, bp[64], ab[1]);
    }
#pragma unroll
    for (int s = 0; s < 2; ++s) {
      const int inner = s * 16 + col;
      const int widx = w * 512 + (inner >> 3) * 128 + (col & 7);
      const float bb = b_base[w * 32 + inner];
#pragma unroll
      for (int r2 = 0; r2 < 4; ++r2) {
        const float v = ab[s][r2] + bb;
        hlin[1][widx + (quad * 4 + r2) * 8] = (_Float16)fmaxf(v, 0.0f);
      }
    }
  }
  __syncthreads();

  if (w == 0) {
    floatx4 ad = (floatx4){0.f, 0.f, 0.f, 0.f};
#pragma unroll
    for (int kt = 0; kt < 8; ++kt) {
      const half8 ahh = *(const half8*)&hlin[1][kt * 512 + lane * 8];
      ad = MFMA16(ahh, wdp[kt * 64 + lane], ad);
    }
    const float bd = (col < 8) ? b_dir[col] : b_mag[col - 8];
#pragma unroll
    for (int r2 = 0; r2 < 4; ++r2) {
      const float v = ad[r2] + bd;
      const float act = (col < 8) ? tanh_fast(v) : sigm(v);
      const float other = __shfl_xor(act, 8, 64);
      if (col < 8)
        out[(size_t)(row0 + quad * 4 + r2) * 8 + col] = act * other;
    }
  }
}

extern "C" void kernel_launch(void* const* d_in, const int* in_sizes, int n_in,
                              void* d_out, int out_size, void* d_ws, size_t ws_size,
                              hipStream_t stream) {
  const float* x_seq  = (const float*)d_in[0];
  const float* b_ih   = (const float*)d_in[3];
  const float* b_hh   = (const float*)d_in[4];
  const float* b_base = (const float*)d_in[6];
  const float* b_dir  = (const float*)d_in[8];
  const float* b_mag  = (const float*)d_in[10];
  _Float16* ws = (_Float16*)d_ws;
  float* out = (float*)d_out;

  hipLaunchKernelGGL(prep_kernel, dim3(616), dim3(64), 0, stream,
                     (const float*)d_in[1], (const float*)d_in[2],
                     (const float*)d_in[5], (const float*)d_in[7],
                     (const float*)d_in[9], ws);

  hipLaunchKernelGGL(gru_all_kernel, dim3(64), dim3(512), 0, stream,
                     x_seq, b_ih, b_hh, b_base, b_dir, b_mag, ws, out);
}

// Round 3
// 4132.056 us; speedup vs baseline: 1.0426x; 1.0426x over previous
//
#include <hip/hip_runtime.h>

#define T_SEQ 512
#define HID 256

typedef _Float16 half8 __attribute__((ext_vector_type(8)));
typedef _Float16 half4 __attribute__((ext_vector_type(4)));
typedef float floatx4 __attribute__((ext_vector_type(4)));

// ws layout (f16 elements): gh frags | gi frags | w_base frags | w_dir/mag frags
#define OFF_GH 0
#define OFF_GI (OFF_GH + 384 * 512)
#define OFF_WB (OFF_GI + 96 * 512)
#define OFF_WD (OFF_WB + 128 * 512)

#define MFMA16(A, B, C) __builtin_amdgcn_mfma_f32_16x16x32_f16(A, B, C, 0, 0, 0)

__device__ __forceinline__ float sigm(float x) { return 1.0f / (1.0f + __expf(-x)); }
__device__ __forceinline__ float tanh_fast(float x) {
  float e = __expf(2.0f * x);
  return 1.0f - 2.0f / (e + 1.0f);
}

// Pack all weights (fp32 in) into f16 MFMA B-fragment order.
__global__ void prep_kernel(const float* __restrict__ w_ih,
                            const float* __restrict__ w_hh,
                            const float* __restrict__ w_base,
                            const float* __restrict__ w_dir,
                            const float* __restrict__ w_mag,
                            _Float16* __restrict__ ws) {
  const int f = blockIdx.x;
  const int lane = threadIdx.x;
  const int col = lane & 15, quad = lane >> 4;
  const float* src;
  int n, k, ld;
  _Float16* dst;
  if (f < 384) {  // w_hh frags: f = (w*8 + kt)*6 + nt ; nt: 0,1=r 2,3=z 4,5=n
    int nt = f % 6, kt = (f / 6) % 8, w = f / 48;
    n = (nt >> 1) * 256 + w * 32 + (nt & 1) * 16 + col;
    k = kt * 32 + quad * 8;
    src = w_hh; ld = 256;
    dst = ws + OFF_GH + ((w * 8 + kt) * 6 + nt) * 512 + lane * 8;
  } else if (f < 480) {  // w_ih frags: f2 = (w*2 + kt)*6 + nt
    int f2 = f - 384;
    int nt = f2 % 6, kt = (f2 / 6) % 2, w = f2 / 12;
    n = (nt >> 1) * 256 + w * 32 + (nt & 1) * 16 + col;
    k = kt * 32 + quad * 8;
    src = w_ih; ld = 64;
    dst = ws + OFF_GI + ((w * 2 + kt) * 6 + nt) * 512 + lane * 8;
  } else if (f < 608) {  // w_base frags
    int f3 = f - 480;
    int nt = f3 % 2, kt = (f3 / 2) % 8, w = f3 / 16;
    n = w * 32 + nt * 16 + col;
    k = kt * 32 + quad * 8;
    src = w_base; ld = 256;
    dst = ws + OFF_WB + ((w * 8 + kt) * 2 + nt) * 512 + lane * 8;
  } else {  // dir/mag combined: cols 0..7 dir, 8..15 mag
    int kt = f - 608;
    k = kt * 32 + quad * 8;
    ld = 256;
    if (col < 8) { src = w_dir; n = col; } else { src = w_mag; n = col - 8; }
    dst = ws + OFF_WD + kt * 512 + lane * 8;
  }
#pragma unroll
  for (int j = 0; j < 8; ++j)
    dst[j] = (_Float16)src[n * ld + k + j];
}

// One GRU step. XCUR/XNEXT are the NAMES of float4[4] arrays (token-pasted, all
// indices compile-time => pure registers; the R2 lambda/pointer-swap version
// put these in scratch: WRITE_SIZE 32MB, 2.7x slowdown). Order: st loads first
// (oldest in vmcnt, so their wait never drains the x prefetch), then x
// prefetch for t+1 (consumed one full body later => zero exposed latency),
// cvt of current x (already resident), gi MFMAs (register-only, cover the ah
// lgkm latency), 40 resident MFMAs, 8 streamed MFMAs.
#define GRU_BODY(XCUR, XNEXT, TPRE, CUR)                                       \
  {                                                                            \
    __syncthreads();                                                           \
    const _Float16* hc = hlin[CUR];                                            \
    _Float16* hn = hlin[(CUR) ^ 1];                                            \
    half8 st[8];                                                               \
    _Pragma("unroll")                                                          \
    for (int i = 0; i < 8; ++i) st[i] = ghp[(40 + i) * 64 + lane];             \
    {                                                                          \
      const float* p = xlane + (size_t)(TPRE) * 64;                            \
      XNEXT[0] = *(const float4*)(p);                                          \
      XNEXT[1] = *(const float4*)(p + 4);                                      \
      XNEXT[2] = *(const float4*)(p + 32);                                     \
      XNEXT[3] = *(const float4*)(p + 36);                                     \
    }                                                                          \
    half8 ax0, ax1;                                                            \
    ax0[0] = (_Float16)XCUR[0].x; ax0[1] = (_Float16)XCUR[0].y;                \
    ax0[2] = (_Float16)XCUR[0].z; ax0[3] = (_Float16)XCUR[0].w;                \
    ax0[4] = (_Float16)XCUR[1].x; ax0[5] = (_Float16)XCUR[1].y;                \
    ax0[6] = (_Float16)XCUR[1].z; ax0[7] = (_Float16)XCUR[1].w;                \
    ax1[0] = (_Float16)XCUR[2].x; ax1[1] = (_Float16)XCUR[2].y;                \
    ax1[2] = (_Float16)XCUR[2].z; ax1[3] = (_Float16)XCUR[2].w;                \
    ax1[4] = (_Float16)XCUR[3].x; ax1[5] = (_Float16)XCUR[3].y;                \
    ax1[6] = (_Float16)XCUR[3].z; ax1[7] = (_Float16)XCUR[3].w;                \
    half8 ah[8];                                                               \
    _Pragma("unroll")                                                          \
    for (int kt = 0; kt < 8; ++kt)                                             \
      ah[kt] = *(const half8*)&hc[kt * 512 + lane * 8];                        \
    floatx4 acc[8];                                                            \
    _Pragma("unroll")                                                          \
    for (int i = 0; i < 8; ++i) acc[i] = (floatx4){0.f, 0.f, 0.f, 0.f};        \
    __builtin_amdgcn_s_setprio(1);                                             \
    _Pragma("unroll")                                                          \
    for (int nt = 0; nt < 6; ++nt) {                                           \
      const int aidx = (nt < 4) ? nt : nt + 2;                                 \
      acc[aidx] = MFMA16(ax0, wg[nt], acc[aidx]);                              \
      acc[aidx] = MFMA16(ax1, wg[6 + nt], acc[aidx]);                          \
    }                                                                          \
    _Pragma("unroll")                                                          \
    for (int f = 0; f < 40; ++f)                                               \
      acc[f % 6] = MFMA16(ah[f / 6], wreg[f], acc[f % 6]);                     \
    _Pragma("unroll")                                                          \
    for (int i = 0; i < 8; ++i) {                                              \
      const int f = 40 + i;                                                    \
      acc[f % 6] = MFMA16(ah[f / 6], st[i], acc[f % 6]);                       \
    }                                                                          \
    __builtin_amdgcn_s_setprio(0);                                             \
    _Pragma("unroll")                                                          \
    for (int s = 0; s < 2; ++s) {                                              \
      const int inner = s * 16 + col;                                          \
      const int widx = w * 512 + (inner >> 3) * 128 + (col & 7);               \
      _Pragma("unroll")                                                        \
      for (int r2 = 0; r2 < 4; ++r2) {                                         \
        const float rr = sigm(acc[0 + s][r2] + br[s]);                         \
        const float zz = sigm(acc[2 + s][r2] + bz[s]);                         \
        const float nn = tanh_fast(acc[6 + s][r2] + bin_[s] +                  \
                                   rr * (acc[4 + s][r2] + bhn[s]));            \
        const float hnew = zz * hreg[s][r2] + (1.0f - zz) * nn;                \
        hreg[s][r2] = hnew;                                                    \
        hn[widx + (quad * 4 + r2) * 8] = (_Float16)hnew;                       \
      }                                                                        \
    }                                                                          \
  }

// Single self-contained sequential kernel: 64 blocks (16 batch rows each) x
// 512 threads, 1 block/CU. Per step: 60 MFMAs — 40 register-resident gh frags,
// 12 register-resident gi (w_ih) frags fed by x prefetched one step ahead,
// 8 gh frags streamed from L2. No gi precompute, no inter-launch state, no
// cross-block communication.
__global__ __launch_bounds__(512, 1)
void gru_all_kernel(const float* __restrict__ x_seq,
                    const float* __restrict__ b_ih,
                    const float* __restrict__ b_hh,
                    const float* __restrict__ b_base,
                    const float* __restrict__ b_dir,
                    const float* __restrict__ b_mag,
                    const _Float16* __restrict__ ws,
                    float* __restrict__ out) {
  __shared__ __align__(16) _Float16 hlin[2][4096];  // [kt(8)][q(4)][row(16)][8]

  const int tid = threadIdx.x;
  const int lane = tid & 63;
  const int w = tid >> 6;
  const int col = lane & 15;
  const int quad = lane >> 4;
  const int row0 = blockIdx.x * 16;

  float br[2], bz[2], bin_[2], bhn[2];
#pragma unroll
  for (int s = 0; s < 2; ++s) {
    const int c = w * 32 + s * 16 + col;
    br[s] = b_ih[c] + b_hh[c];
    bz[s] = b_ih[256 + c] + b_hh[256 + c];
    bin_[s] = b_ih[512 + c];
    bhn[s] = b_hh[512 + c];
  }

  float hreg[2][4];
#pragma unroll
  for (int s = 0; s < 2; ++s)
#pragma unroll
    for (int r2 = 0; r2 < 4; ++r2) hreg[s][r2] = 0.0f;
  *(half8*)&hlin[0][tid * 8] = (half8)((_Float16)0.0f);

  const half8* __restrict__ ghp = (const half8*)(ws + OFF_GH) + w * (48 * 64);
  const half8* __restrict__ gip = (const half8*)(ws + OFF_GI) + w * (12 * 64);
  const half8* __restrict__ wbp = (const half8*)(ws + OFF_WB) + w * (16 * 64);
  const half8* __restrict__ wdp = (const half8*)(ws + OFF_WD);

  // register-resident weights: 40 gh frags + all 12 gi frags (AGPR side)
  half8 wreg[40];
#pragma unroll
  for (int f = 0; f < 40; ++f) wreg[f] = ghp[f * 64 + lane];
  half8 wg[12];
#pragma unroll
  for (int f = 0; f < 12; ++f) wg[f] = gip[f * 64 + lane];

  const float* const xlane =
      x_seq + (size_t)(row0 + col) * (T_SEQ * 64) + quad * 8;
  float4 xc[4], xn[4];
  {
    const float* p = xlane;  // t = 0
    xc[0] = *(const float4*)(p);
    xc[1] = *(const float4*)(p + 4);
    xc[2] = *(const float4*)(p + 32);
    xc[3] = *(const float4*)(p + 36);
  }

#pragma unroll 1
  for (int t = 0; t < T_SEQ; t += 2) {
    GRU_BODY(xc, xn, t + 1, 0);
    const int tp2 = (t + 2 < T_SEQ) ? (t + 2) : (T_SEQ - 1);
    GRU_BODY(xn, xc, tp2, 1);
  }

  __syncthreads();
  // head: base = relu(hT @ w_base^T + b_base); h_T in hlin[0] (T even)
  {
    floatx4 ab[2];
    ab[0] = (floatx4){0.f, 0.f, 0.f, 0.f};
    ab[1] = (floatx4){0.f, 0.f, 0.f, 0.f};
#pragma unroll
    for (int kt = 0; kt < 8; ++kt) {
      const half8 ahh = *(const half8*)&hlin[0][kt * 512 + lane * 8];
      const half8* bp = wbp + kt * (2 * 64) + lane;
      ab[0] = MFMA16(ahh, bp[0],  ab[0]);
      ab[1] = MFMA16(ahh, bp[64], ab[1]);
    }
#pragma unroll
    for (int s = 0; s < 2; ++s) {
      const int inner = s * 16 + col;
      const int widx = w * 512 + (inner >> 3) * 128 + (col & 7);
      const float bb = b_base[w * 32 + inner];
#pragma unroll
      for (int r2 = 0; r2 < 4; ++r2) {
        const float v = ab[s][r2] + bb;
        hlin[1][widx + (quad * 4 + r2) * 8] = (_Float16)fmaxf(v, 0.0f);
      }
    }
  }
  __syncthreads();

  if (w == 0) {
    floatx4 ad = (floatx4){0.f, 0.f, 0.f, 0.f};
#pragma unroll
    for (int kt = 0; kt < 8; ++kt) {
      const half8 ahh = *(const half8*)&hlin[1][kt * 512 + lane * 8];
      ad = MFMA16(ahh, wdp[kt * 64 + lane], ad);
    }
    const float bd = (col < 8) ? b_dir[col] : b_mag[col - 8];
#pragma unroll
    for (int r2 = 0; r2 < 4; ++r2) {
      const float v = ad[r2] + bd;
      const float act = (col < 8) ? tanh_fast(v) : sigm(v);
      const float other = __shfl_xor(act, 8, 64);
      if (col < 8)
        out[(size_t)(row0 + quad * 4 + r2) * 8 + col] = act * other;
    }
  }
}

extern "C" void kernel_launch(void* const* d_in, const int* in_sizes, int n_in,
                              void* d_out, int out_size, void* d_ws, size_t ws_size,
                              hipStream_t stream) {
  const float* x_seq  = (const float*)d_in[0];
  const float* b_ih   = (const float*)d_in[3];
  const float* b_hh   = (const float*)d_in[4];
  const float* b_base = (const float*)d_in[6];
  const float* b_dir  = (const float*)d_in[8];
  const float* b_mag  = (const float*)d_in[10];
  _Float16* ws = (_Float16*)d_ws;
  float* out = (float*)d_out;

  hipLaunchKernelGGL(prep_kernel, dim3(616), dim3(64), 0, stream,
                     (const float*)d_in[1], (const float*)d_in[2],
                     (const float*)d_in[5], (const float*)d_in[7],
                     (const float*)d_in[9], ws);

  hipLaunchKernelGGL(gru_all_kernel, dim3(64), dim3(512), 0, stream,
                     x_seq, b_ih, b_hh, b_base, b_dir, b_mag, ws, out);
}